// Round 1
// baseline (356.566 us; speedup 1.0000x reference)
//
#include <hip/hip_runtime.h>

// ---------------------------------------------------------------------------
// Payoff_Net: h = leakyrelu(x@W1+b1); p = h@W2+b2; P = antisym(p);
// 100 iters: u=softmax(-P v); v=softmax(P^T u)  [P^T=-P => both w<-softmax(-P w)]
// out = concat(u,v)
// ---------------------------------------------------------------------------

typedef __attribute__((ext_vector_type(8))) short bf16x8;
typedef __attribute__((ext_vector_type(4))) float f32x4;

#define LOG2E 1.4426950408889634f

__device__ __forceinline__ f32x4 mfma16(bf16x8 a, bf16x8 b, f32x4 c) {
  return __builtin_amdgcn_mfma_f32_16x16x32_bf16(a, b, c, 0, 0, 0);
}
__device__ __forceinline__ unsigned int pkbf(float lo, float hi) {
  unsigned int r;
  asm("v_cvt_pk_bf16_f32 %0, %1, %2" : "=v"(r) : "v"(lo), "v"(hi));
  return r;
}
__device__ __forceinline__ float fexp2(float x) {
  float r; asm("v_exp_f32 %0, %1" : "=v"(r) : "v"(x)); return r;
}
__device__ __forceinline__ float frcp(float x) {
  float r; asm("v_rcp_f32 %0, %1" : "=v"(r) : "v"(x)); return r;
}
// strict-upper-tri row-major index for n=64: (i<j)
__device__ __forceinline__ int tidx(int i, int j) {
  return i*63 - ((i*(i-1))>>1) + (j - i - 1);
}

// --------------------------- h = leakyrelu(x@W1+b1) ------------------------
// block 256 = 4 waves; block tile 16 rows x 128 cols; wave: 4 rows x 128 cols
__global__ __launch_bounds__(256) void kern_h(
    const float* __restrict__ x, const float* __restrict__ W1,
    const float* __restrict__ b1, float* __restrict__ h) {
  const int rb   = blockIdx.x;            // 16 rows per block
  const int wv   = threadIdx.x >> 6;      // wave -> rows wv*4..wv*4+3
  const int lane = threadIdx.x & 63;
  const int c0   = lane * 2;
  const float* xb = x + (size_t)(rb*16 + wv*4) * 128;
  float acc[4][2] = {{0.f,0.f},{0.f,0.f},{0.f,0.f},{0.f,0.f}};
  for (int k = 0; k < 128; ++k) {
    float2 w = *reinterpret_cast<const float2*>(W1 + (size_t)k*128 + c0);
    #pragma unroll
    for (int r = 0; r < 4; ++r) {
      float xv = xb[r*128 + k];           // wave-uniform -> scalar load
      acc[r][0] += xv * w.x;
      acc[r][1] += xv * w.y;
    }
  }
  float2 bv = *reinterpret_cast<const float2*>(b1 + c0);
  #pragma unroll
  for (int r = 0; r < 4; ++r) {
    float v0 = acc[r][0] + bv.x, v1 = acc[r][1] + bv.y;
    v0 = (v0 >= 0.f) ? v0 : 0.1f * v0;
    v1 = (v1 >= 0.f) ? v1 : 0.1f * v1;
    float2 st; st.x = v0; st.y = v1;
    *reinterpret_cast<float2*>(h + (size_t)(rb*16 + wv*4 + r)*128 + c0) = st;
  }
}

// --------------------------- p = bf16(h@W2+b2) ------------------------------
// 1 wave per block; wave tile 16 rows x 256 cols; h rows wave-uniform (SGPR)
__global__ __launch_bounds__(64) void kern_p(
    const float* __restrict__ h, const float* __restrict__ W2,
    const float* __restrict__ b2, unsigned short* __restrict__ p) {
  const int rb   = blockIdx.x;            // 16 rows
  const int cb   = blockIdx.y;            // 256-col group
  const int lane = threadIdx.x;
  const int c0   = cb*256 + lane*4;
  if (c0 >= 2016) return;
  const float* hb = h + (size_t)rb * 16 * 128;
  float acc[16][4];
  #pragma unroll
  for (int r = 0; r < 16; ++r)
    { acc[r][0]=0.f; acc[r][1]=0.f; acc[r][2]=0.f; acc[r][3]=0.f; }
  for (int k = 0; k < 128; ++k) {
    float4 w = *reinterpret_cast<const float4*>(W2 + (size_t)k*2016 + c0);
    #pragma unroll
    for (int r = 0; r < 16; ++r) {
      float hv = hb[r*128 + k];           // wave-uniform -> scalar load
      acc[r][0] += hv * w.x; acc[r][1] += hv * w.y;
      acc[r][2] += hv * w.z; acc[r][3] += hv * w.w;
    }
  }
  float4 bv = *reinterpret_cast<const float4*>(b2 + c0);
  #pragma unroll
  for (int r = 0; r < 16; ++r) {
    float v0 = acc[r][0]+bv.x, v1 = acc[r][1]+bv.y;
    float v2 = acc[r][2]+bv.z, v3 = acc[r][3]+bv.w;
    uint2 st; st.x = pkbf(v0, v1); st.y = pkbf(v2, v3);
    *reinterpret_cast<uint2*>(p + (size_t)(rb*16 + r)*2016 + c0) = st;
  }
}

// --------------------------- QRE solver -------------------------------------
// 1 wave per batch item, 4 items per block. A = -P in bf16 MFMA A-frags,
// K-index sigma-permuted so C-layout == next B-layout (no LDS/barriers in loop).
// 5th all-ones M-tile yields s = sum(w) from the same MFMA.
__global__ __launch_bounds__(256) void kern_solve(
    const unsigned short* __restrict__ p, float* __restrict__ out) {
  __shared__ unsigned short ps[4*2016];
  const int tid  = threadIdx.x;
  const int wv   = tid >> 6;
  const int lane = tid & 63;
  const int g    = lane >> 4;   // k-group / col-group
  const int ri   = lane & 15;   // A row within tile / C col

  // stage p for this block's 4 items (coalesced u32 loads)
  {
    const unsigned int* pg =
        reinterpret_cast<const unsigned int*>(p + (size_t)blockIdx.x * (4*2016));
    unsigned int* psu = reinterpret_cast<unsigned int*>(ps);
    for (int i = tid; i < (4*2016)/2; i += 256) psu[i] = pg[i];
  }
  __syncthreads();

  const unsigned short* pw = ps + wv * 2016;

  // A-frags: A[row][sigma(kappa)] = -P[row][jl]
  // sigma: kappa=(kt,g,j) -> jl = 4g + (j&3) + 16*(2kt + (j>>2))
  bf16x8 afr[4][2];
  #pragma unroll
  for (int mt = 0; mt < 4; ++mt) {
    #pragma unroll
    for (int kt = 0; kt < 2; ++kt) {
      union { bf16x8 v; unsigned short u[8]; } f;
      const int row = mt*16 + ri;
      #pragma unroll
      for (int j = 0; j < 8; ++j) {
        const int jl = 4*g + (j&3) + 16*(2*kt + (j>>2));
        unsigned short val;
        if (row < jl)      val = (unsigned short)(pw[tidx(row, jl)] ^ 0x8000u);
        else if (row > jl) val = pw[tidx(jl, row)];
        else               val = 0;
        f.u[j] = val;
      }
      afr[mt][kt] = f.v;
    }
  }
  bf16x8 ones;
  {
    union { bf16x8 v; unsigned short u[8]; } f;
    #pragma unroll
    for (int j = 0; j < 8; ++j) f.u[j] = 0x3F80;  // bf16 1.0
    ones = f.v;
  }

  // e[mt][r] holds (unnormalized) w at logical row i = 16*mt + 4*g + r
  float e[4][4];
  #pragma unroll
  for (int mt = 0; mt < 4; ++mt)
    #pragma unroll
    for (int r = 0; r < 4; ++r) e[mt][r] = 0.015625f;  // w0 = 1/64

  const size_t item = (size_t)blockIdx.x * 4 + wv;
  float* op = out + item * 128;

  const f32x4 z = {0.f, 0.f, 0.f, 0.f};

  #pragma unroll 1
  for (int it = 1; it <= 200; ++it) {
    union { bf16x8 v; unsigned int u[4]; } B0, B1;
    B0.u[0] = pkbf(e[0][0], e[0][1]); B0.u[1] = pkbf(e[0][2], e[0][3]);
    B0.u[2] = pkbf(e[1][0], e[1][1]); B0.u[3] = pkbf(e[1][2], e[1][3]);
    B1.u[0] = pkbf(e[2][0], e[2][1]); B1.u[1] = pkbf(e[2][2], e[2][3]);
    B1.u[2] = pkbf(e[3][0], e[3][1]); B1.u[3] = pkbf(e[3][2], e[3][3]);

    f32x4 acc0 = mfma16(afr[0][0], B0.v, z); acc0 = mfma16(afr[0][1], B1.v, acc0);
    f32x4 acc1 = mfma16(afr[1][0], B0.v, z); acc1 = mfma16(afr[1][1], B1.v, acc1);
    f32x4 acc2 = mfma16(afr[2][0], B0.v, z); acc2 = mfma16(afr[2][1], B1.v, acc2);
    f32x4 acc3 = mfma16(afr[3][0], B0.v, z); acc3 = mfma16(afr[3][1], B1.v, acc3);
    f32x4 accS = mfma16(ones,      B0.v, z); accS = mfma16(ones,      B1.v, accS);

    const float s  = accS[0];          // s = sum of previous (unnormalized) w
    const float rs = frcp(s);

    if (it == 200) {                   // u = w_199 = e_199 / s_200
      if (ri == 0) {
        #pragma unroll
        for (int mt = 0; mt < 4; ++mt) {
          float4 st;
          st.x = e[mt][0]*rs; st.y = e[mt][1]*rs;
          st.z = e[mt][2]*rs; st.w = e[mt][3]*rs;
          *reinterpret_cast<float4*>(op + mt*16 + g*4) = st;
        }
      }
    }

    const float cc = rs * LOG2E;       // exp(y/s) = exp2(y * rs * log2e)
    float t;
    t = acc0[0]*cc; e[0][0] = fexp2(t);  t = acc0[1]*cc; e[0][1] = fexp2(t);
    t = acc0[2]*cc; e[0][2] = fexp2(t);  t = acc0[3]*cc; e[0][3] = fexp2(t);
    t = acc1[0]*cc; e[1][0] = fexp2(t);  t = acc1[1]*cc; e[1][1] = fexp2(t);
    t = acc1[2]*cc; e[1][2] = fexp2(t);  t = acc1[3]*cc; e[1][3] = fexp2(t);
    t = acc2[0]*cc; e[2][0] = fexp2(t);  t = acc2[1]*cc; e[2][1] = fexp2(t);
    t = acc2[2]*cc; e[2][2] = fexp2(t);  t = acc2[3]*cc; e[2][3] = fexp2(t);
    t = acc3[0]*cc; e[3][0] = fexp2(t);  t = acc3[1]*cc; e[3][1] = fexp2(t);
    t = acc3[2]*cc; e[3][2] = fexp2(t);  t = acc3[3]*cc; e[3][3] = fexp2(t);
  }

  // v = w_200 = e_200 / s_201 ; s_201 via in-lane + cross-group sum (one-time)
  float sl = 0.f;
  #pragma unroll
  for (int mt = 0; mt < 4; ++mt)
    #pragma unroll
    for (int r = 0; r < 4; ++r) sl += e[mt][r];
  sl += __shfl_xor(sl, 16, 64);
  sl += __shfl_xor(sl, 32, 64);
  const float rv = frcp(sl);
  if (ri == 0) {
    #pragma unroll
    for (int mt = 0; mt < 4; ++mt) {
      float4 st;
      st.x = e[mt][0]*rv; st.y = e[mt][1]*rv;
      st.z = e[mt][2]*rv; st.w = e[mt][3]*rv;
      *reinterpret_cast<float4*>(op + 64 + mt*16 + g*4) = st;
    }
  }
}

// ---------------------------------------------------------------------------
extern "C" void kernel_launch(void* const* d_in, const int* in_sizes, int n_in,
                              void* d_out, int out_size, void* d_ws, size_t ws_size,
                              hipStream_t stream) {
  const float* x  = (const float*)d_in[0];
  const float* W1 = (const float*)d_in[1];
  const float* b1 = (const float*)d_in[2];
  const float* W2 = (const float*)d_in[3];
  const float* b2 = (const float*)d_in[4];
  float* out = (float*)d_out;

  float* h = (float*)d_ws;                                            // 4 MiB
  unsigned short* p =
      (unsigned short*)((char*)d_ws + (size_t)8192 * 128 * 4);        // 31.5 MiB

  kern_h   <<<dim3(512),    dim3(256), 0, stream>>>(x, W1, b1, h);
  kern_p   <<<dim3(512, 8), dim3(64),  0, stream>>>(h, W2, b2, p);
  kern_solve<<<dim3(2048),  dim3(256), 0, stream>>>(p, out);
}